// Round 3
// baseline (10279.272 us; speedup 1.0000x reference)
//
#include <hip/hip_runtime.h>
#include <stdint.h>

// Problem: D-FPS. points_xyz (16, 131072, 3) fp32 -> indices (16, 4096) int32.
//
// Round 17 = round 16 (7062 us) with two critical-path trims, protocol
// skeleton (relaxed-only, tagged words, ring-2 by parity, ONE polling wave)
// unchanged:
//  1. Slot padding: each block's slot is its own 128B line (was: all 16
//     publishers storing into ONE line -> serialized cross-CU writes at the
//     coherence point; last store gates every poller).
//  2. Coords-in-slot: publisher ships the winning point's xyz (from its LDS)
//     in 3 self-tagged u64 words; pollers recover the centroid from the
//     reduce + LDS, eliminating the dependent ~250cy L2 centroid load after
//     barrier2. Payload: w0=dist|idx|tag, w1=x|y_hi17|tag, w2=z|y_lo15|tag.
//     Every word single-writer + self-tagged -> same ordering argument as r8.
// r16 post-mortem: DPP reduction replaced shfl butterflies, -20% (matched
// prediction). r15 post-mortem: widening fan-in / co-residency = 2.5x
// REGRESSION; fan-in stays 16, one block per CU.
//
// Locked-in lessons (r2-r16):
//  - relaxed-only AGENT atomics; tag in every polled word (r7/r8).
//  - ONE relaxed polling wave per block (r5/r10); NARROW fan-in (r15).
//  - hardware barrier beats software tag-spin for intra-block ordering (r13).
//  - one block per CU; co-residency of independent batches regresses (r15).
//  - DPP (VALU-pipe) reductions, never __shfl chains (r16).
//  - points in LDS SoA; allocator never keeps them register-resident (r3-r5).
//  - FMA-chain distance d = fma(dz,dz, fma(dy,dy, dx*dx)), subs exact-rounded
//    (r2: bit-exact vs reference trajectory).
//  - removals help; rearrangements and added traffic regress (r9-r12).

#define BATCH 16
#define NPTS  131072
#define NSAMP 4096
#define NBLK  16                  // blocks per batch
#define TPB   1024                // 16 waves
#define CHUNK (NPTS / NBLK)       // 8192 points per block
#define PPT   (CHUNK / TPB)       // 8 points per thread
#define NWAVE (TPB / 64)
#define SLOT_U64 16               // 128B per block-slot (own cache line)

typedef unsigned long long u64;
typedef unsigned int u32;

// ---- DPP 64-bit lexicographic max-reduce helpers --------------------------
// key = dist_bits(32) | ~gi(32): u64 max == (max dist, then min index).
// update_dpp(old=0,...): lanes with no valid source read 0; all real keys
// are > 0, so 0 is the identity.
#define DPP_ROW_SHR(n)  (0x110 | (n))
#define DPP_BCAST15     0x142
#define DPP_BCAST31     0x143

template <int CTRL>
__device__ __forceinline__ u64 dpp_max_step(u64 key) {
    u32 lo = (u32)key, hi = (u32)(key >> 32);
    u32 olo = (u32)__builtin_amdgcn_update_dpp(0, (int)lo, CTRL, 0xF, 0xF, false);
    u32 ohi = (u32)__builtin_amdgcn_update_dpp(0, (int)hi, CTRL, 0xF, 0xF, false);
    u64 o = ((u64)ohi << 32) | (u64)olo;
    return o > key ? o : key;
}

// Full-wave (64 lane) max; result valid in lane 63.
__device__ __forceinline__ u64 dpp_max64(u64 key) {
    key = dpp_max_step<DPP_ROW_SHR(1)>(key);
    key = dpp_max_step<DPP_ROW_SHR(2)>(key);
    key = dpp_max_step<DPP_ROW_SHR(4)>(key);
    key = dpp_max_step<DPP_ROW_SHR(8)>(key);
    key = dpp_max_step<DPP_BCAST15>(key);
    key = dpp_max_step<DPP_BCAST31>(key);
    return key;
}

// Row (16 lane) max over lanes 0..15 (others must hold 0); valid in lane 15.
__device__ __forceinline__ u64 dpp_max16(u64 key) {
    key = dpp_max_step<DPP_ROW_SHR(1)>(key);
    key = dpp_max_step<DPP_ROW_SHR(2)>(key);
    key = dpp_max_step<DPP_ROW_SHR(4)>(key);
    key = dpp_max_step<DPP_ROW_SHR(8)>(key);
    return key;
}

// Slot layout per (batch, parity, block): 16 u64 = 128B own line; words:
//   word0: dist(32) | idx(17) | tag(15)
//   word1: x(32)    | y_hi(17)| tag(15)
//   word2: z(32)    | y_lo(15) << 17 | pad(2) | tag(15)
// Poison 0xAA.. -> tag 0x2AAA; zero-init -> tag 0; live tags are 1..4095.

__global__ void fps_init_kernel(u64* __restrict__ ws) {
    int i = blockIdx.x * blockDim.x + threadIdx.x;
    if (i < BATCH * 2 * NBLK * SLOT_U64) ws[i] = 0ull;
}

__global__ __launch_bounds__(TPB, 4) void fps_kernel(
        const float* __restrict__ xyz, int* __restrict__ out,
        u64* __restrict__ gslot) {
    const int blk   = blockIdx.x;
    const int b     = blk & 15;    // batch: a batch's 16 blocks share blk%8
    const int chunk = blk >> 4;    //        -> same XCD (round-robin dispatch)
    const int tid   = threadIdx.x;
    const int w     = tid >> 6;
    const int lane  = tid & 63;

    const float* bxyz = xyz + (size_t)b * NPTS * 3;
    const int base = chunk * CHUNK;

    // ---- LDS: SoA points + plain red keys + plain bc (all barrier-ordered) --
    __shared__ float2 sxy[CHUNK];          // 64 KB
    __shared__ float  szz[CHUNK];          // 32 KB
    __shared__ u64 red[NWAVE];
    __shared__ u32 bc[4];                  // x_bits, y_hi, z_bits, y_lo
    for (int i = tid; i < CHUNK; i += TPB) {
        size_t p = (size_t)(base + i) * 3;
        sxy[i] = make_float2(bxyz[p + 0], bxyz[p + 1]);
        szz[i] = bxyz[p + 2];
    }
    if (tid == 0 && chunk == 0) out[b * NSAMP] = 0; // iter 0 emits index 0
    __syncthreads();   // staging visibility

    float pd[PPT];
#pragma unroll
    for (int k = 0; k < PPT; ++k) pd[k] = __builtin_inff();

    float cx = bxyz[0], cy = bxyz[1], cz = bxyz[2];

    u64* gs = gslot + (size_t)b * 2 * NBLK * SLOT_U64;   // [2][NBLK][16]

    for (int it = 1; it < NSAMP; ++it) {
        const int par = it & 1;
        u64* gsp = gs + par * NBLK * SLOT_U64;

        // ---- update min-dists + local argmax (LDS + registers) ----
        // Verified arithmetic (round 2, absmax 0): FMA-contracted
        //   d = fma(dz,dz, fma(dy,dy, dx*dx)), subs exact-rounded.
        float bd = -1.0f;
        int   bk = 0;
#pragma unroll
        for (int k = 0; k < PPT; ++k) {
            int i = tid + TPB * k;
            float2 xy = sxy[i];
            float  z  = szz[i];
            float dx = __fsub_rn(xy.x, cx);
            float dy = __fsub_rn(xy.y, cy);
            float dz = __fsub_rn(z,    cz);
            float d  = __builtin_fmaf(dz, dz,
                         __builtin_fmaf(dy, dy, __fmul_rn(dx, dx)));
            float nd = fminf(pd[k], d);
            pd[k] = nd;
            // strict >: earliest k wins (gi ascends with k) = first-occurrence
            if (nd > bd) { bd = nd; bk = k; }
        }
        u32 gi = (u32)(base + tid + TPB * bk);
        u64 key = ((u64)__float_as_uint(bd) << 32) | (u64)(~gi);

        // ---- wave max via DPP (VALU pipe) ----
        key = dpp_max64(key);              // valid in lane 63
        if (lane == 63) red[w] = key;      // plain store; barrier1 orders it
        __syncthreads();                   // barrier1

        if (w == 0) {
            // ---- combine 16 plain keys (real keys > 0; lanes 16+ feed 0) ----
            u64 k2 = (lane < NWAVE) ? red[lane] : 0ull;
            k2 = dpp_max16(k2);            // valid in lane 15
            // ---- publish key + winner coords (3 self-tagged words) ----
            if (lane == 15) {
                u32 db  = (u32)(k2 >> 32);
                u32 idx = ~(u32)k2;        // = gi (fits 17 bits)
                float2 xy = sxy[idx - base];   // own chunk's winner coords
                float  z  = szz[idx - base];
                u32 xb = __float_as_uint(xy.x);
                u32 yb = __float_as_uint(xy.y);
                u32 zb = __float_as_uint(z);
                u64* slot = gsp + chunk * SLOT_U64;
                u64 t = (u64)it;
                __hip_atomic_store(&slot[1],
                    ((u64)xb << 32) | ((u64)(yb >> 15) << 15) | t,
                    __ATOMIC_RELAXED, __HIP_MEMORY_SCOPE_AGENT);
                __hip_atomic_store(&slot[2],
                    ((u64)zb << 32) | ((u64)(yb & 0x7FFFu) << 17) | t,
                    __ATOMIC_RELAXED, __HIP_MEMORY_SCOPE_AGENT);
                __hip_atomic_store(&slot[0],
                    ((u64)db << 32) | ((u64)idx << 15) | t,
                    __ATOMIC_RELAXED, __HIP_MEMORY_SCOPE_AGENT);
            }
            // ---- relaxed poll: 48 lanes cover 16 blocks x 3 words ----
            const int pb = lane & 15;      // block
            const int pw = lane >> 4;      // word 0..2 (lanes 48+ idle)
            u64* paddr = gsp + pb * SLOT_U64 + pw;
            u64 v; bool ok;
            do {
                v  = (lane < 48)
                       ? __hip_atomic_load(paddr, __ATOMIC_RELAXED,
                                           __HIP_MEMORY_SCOPE_AGENT)
                       : 0ull;
                ok = (lane < 48) ? ((v & 0x7FFFull) == (u64)it) : true;
            } while (__ballot(ok) != ~0ull);
            // keys from word0 lanes; 0 elsewhere
            u64 k3 = 0ull;
            if (pw == 0) {
                u32 db  = (u32)(v >> 32);
                u32 idx = (u32)((v >> 15) & 0x1FFFFu);
                k3 = ((u64)db << 32) | (u64)(~idx);
            }
            // reduce lanes 0..15, then bcast winner key to lanes 16..63
            k3 = dpp_max16(k3);                      // lane 15
            k3 = dpp_max_step<DPP_BCAST15>(k3);      // -> lanes 16..31
            k3 = dpp_max_step<DPP_BCAST31>(k3);      // -> lanes 32..63
            u32 widx = ~(u32)k3;
            int  wb   = (int)(widx >> 13);           // winning block (CHUNK=8192)
            if (lane == 15 && chunk == 0) out[b * NSAMP + it] = (int)widx;
            if (pw == 1 && pb == wb) {               // holder of x | y_hi
                bc[0] = (u32)(v >> 32);
                bc[1] = (u32)((v >> 15) & 0x1FFFFu);
            }
            if (pw == 2 && pb == wb) {               // holder of z | y_lo
                bc[2] = (u32)(v >> 32);
                bc[3] = (u32)((v >> 17) & 0x7FFFu);
            }
        }
        __syncthreads();                   // barrier2 orders bc[] for all waves

        cx = __uint_as_float(bc[0]);       // centroid from LDS (was L2 load)
        cy = __uint_as_float((bc[1] << 15) | bc[3]);
        cz = __uint_as_float(bc[2]);
    }
}

extern "C" void kernel_launch(void* const* d_in, const int* in_sizes, int n_in,
                              void* d_out, int out_size, void* d_ws, size_t ws_size,
                              hipStream_t stream) {
    const float* xyz = (const float*)d_in[0];
    int* out = (int*)d_out;
    u64* gslot = (u64*)d_ws;   // [BATCH][2][NBLK][SLOT_U64] u64 = 64 KB

    hipLaunchKernelGGL(fps_init_kernel, dim3(8), dim3(1024), 0, stream, gslot);
    hipLaunchKernelGGL(fps_kernel, dim3(BATCH * NBLK), dim3(TPB), 0, stream,
                       xyz, out, gslot);
}

// Round 5
// 6871.225 us; speedup vs baseline: 1.4960x; 1.4960x over previous
//
#include <hip/hip_runtime.h>
#include <stdint.h>

// Problem: D-FPS. points_xyz (16, 131072, 3) fp32 -> indices (16, 4096) int32.
//
// Round 19 = round 18 resubmitted verbatim (round 18's bench was an
// infrastructure failure: "MI355X container failed twice" — no measurement).
//
// Round 18 = round 16 (7062 us) with the distance loop's LDS reads removed:
// each thread's 8 points are loop-invariant -> load them ONCE into registers
// (px/py/pz[8], 24 VGPRs) and never touch LDS in the steady-state loop.
// r16's 16 DS instrs/thread/iter (~1500 cy/iter of serialized DS-pipe time at
// m134 rates) drop to zero; distance phase becomes pure VALU overlapped 4
// waves/SIMD. LDS staging arrays are KEPT (written once, read once into regs)
// as residency ballast so the measured 1-block/CU structure is unchanged.
// Register-residency is forced via full unroll + compile-time indices only
// (r3-r5's failure = runtime indexing -> scratch; rule #20).
// Cross-block protocol BYTE-IDENTICAL to r16 (= r8/r13/r14 skeleton).
//
// r17 post-mortem (10279 us, REVERTED): padding slots to 16 lines + 3-word
// coords-in-slot made every poll round fetch 16x the lines (FETCH 16->145MB).
// Lesson: the poll must touch exactly ONE cache line; 16 slots in one line is
// the optimal poll topology, write-sharing be damned.
//
// Locked-in lessons (r2-r17):
//  - relaxed-only AGENT atomics; tag in every polled word (r7/r8).
//  - ONE relaxed polling wave per block; poll touches ONE line (r5/r10/r17).
//  - NARROW fan-in: 16 publishers; no co-residency (r15).
//  - hardware barrier beats software tag-spin for intra-block ordering (r13).
//  - DPP (VALU-pipe) reductions, never __shfl chains (r16).
//  - FMA-chain distance d = fma(dz,dz, fma(dy,dy, dx*dx)), subs exact-rounded
//    (r2: bit-exact vs reference trajectory).
//  - removals help; rearrangements and added traffic regress (r9-r12, r17).

#define BATCH 16
#define NPTS  131072
#define NSAMP 4096
#define NBLK  16                  // blocks per batch
#define TPB   1024                // 16 waves
#define CHUNK (NPTS / NBLK)       // 8192 points per block
#define PPT   (CHUNK / TPB)       // 8 points per thread
#define NWAVE (TPB / 64)

typedef unsigned long long u64;
typedef unsigned int u32;

// ---- DPP 64-bit lexicographic max-reduce helpers --------------------------
// key = dist_bits(32) | ~gi(32): u64 max == (max dist, then min index).
// update_dpp(old=0,...): lanes with no valid source read 0; all real keys
// are > 0, so 0 is the identity.
#define DPP_ROW_SHR(n)  (0x110 | (n))
#define DPP_BCAST15     0x142
#define DPP_BCAST31     0x143

template <int CTRL>
__device__ __forceinline__ u64 dpp_max_step(u64 key) {
    u32 lo = (u32)key, hi = (u32)(key >> 32);
    u32 olo = (u32)__builtin_amdgcn_update_dpp(0, (int)lo, CTRL, 0xF, 0xF, false);
    u32 ohi = (u32)__builtin_amdgcn_update_dpp(0, (int)hi, CTRL, 0xF, 0xF, false);
    u64 o = ((u64)ohi << 32) | (u64)olo;
    return o > key ? o : key;
}

// Full-wave (64 lane) max; result valid in lane 63.
__device__ __forceinline__ u64 dpp_max64(u64 key) {
    key = dpp_max_step<DPP_ROW_SHR(1)>(key);
    key = dpp_max_step<DPP_ROW_SHR(2)>(key);
    key = dpp_max_step<DPP_ROW_SHR(4)>(key);
    key = dpp_max_step<DPP_ROW_SHR(8)>(key);
    key = dpp_max_step<DPP_BCAST15>(key);
    key = dpp_max_step<DPP_BCAST31>(key);
    return key;
}

// Row (16 lane) max over lanes 0..15 (others must hold 0); valid in lane 15.
__device__ __forceinline__ u64 dpp_max16(u64 key) {
    key = dpp_max_step<DPP_ROW_SHR(1)>(key);
    key = dpp_max_step<DPP_ROW_SHR(2)>(key);
    key = dpp_max_step<DPP_ROW_SHR(4)>(key);
    key = dpp_max_step<DPP_ROW_SHR(8)>(key);
    return key;
}

// Global slot word (8B, one per block per parity):
//   [63:32] dist bits (>=0 -> monotone) | [31:15] idx (17b) | [14:0] iter tag
// Poison 0xAA.. -> tag 0x2AAA; zero-init -> tag 0; live tags are 1..4095.
// Ring-2 by parity; ordering via the value-dependence chain (r8-proven).

__global__ void fps_init_kernel(u64* __restrict__ ws) {
    int i = blockIdx.x * blockDim.x + threadIdx.x;
    if (i < BATCH * 2 * NBLK) ws[i] = 0ull;
}

__global__ __launch_bounds__(TPB, 4) void fps_kernel(
        const float* __restrict__ xyz, int* __restrict__ out,
        u64* __restrict__ gslot) {
    const int blk   = blockIdx.x;
    const int b     = blk & 15;    // batch: a batch's 16 blocks share blk%8
    const int chunk = blk >> 4;    //        -> same XCD (round-robin dispatch)
    const int tid   = threadIdx.x;
    const int w     = tid >> 6;
    const int lane  = tid & 63;

    const float* bxyz = xyz + (size_t)b * NPTS * 3;
    const int base = chunk * CHUNK;

    // ---- LDS: staging (read once into regs; kept as residency ballast) ----
    __shared__ float2 sxy[CHUNK];          // 64 KB
    __shared__ float  szz[CHUNK];          // 32 KB
    __shared__ u64 red[NWAVE];
    __shared__ u32 bc;                     // winning index, barrier-ordered
    for (int i = tid; i < CHUNK; i += TPB) {
        size_t p = (size_t)(base + i) * 3;
        sxy[i] = make_float2(bxyz[p + 0], bxyz[p + 1]);
        szz[i] = bxyz[p + 2];
    }
    if (tid == 0 && chunk == 0) out[b * NSAMP] = 0; // iter 0 emits index 0
    __syncthreads();   // staging visibility

    // ---- hoist this thread's 8 loop-invariant points into VGPRs ----
    // Full unroll, compile-time indices only (rule #20: runtime-indexed
    // arrays go to scratch). 24 VGPRs.
    float px[PPT], py[PPT], pz[PPT], pd[PPT];
#pragma unroll
    for (int k = 0; k < PPT; ++k) {
        int i = tid + TPB * k;
        float2 xy = sxy[i];
        px[k] = xy.x;
        py[k] = xy.y;
        pz[k] = szz[i];
        pd[k] = __builtin_inff();
    }

    float cx = bxyz[0], cy = bxyz[1], cz = bxyz[2];

    u64* gs = gslot + (size_t)b * 2 * NBLK;   // [2][NBLK]

    for (int it = 1; it < NSAMP; ++it) {
        const int par = it & 1;
        u64* gsp = gs + par * NBLK;

        // ---- update min-dists + local argmax (registers only, no LDS) ----
        // Verified arithmetic (round 2, absmax 0): FMA-contracted
        //   d = fma(dz,dz, fma(dy,dy, dx*dx)), subs exact-rounded.
        float bd = -1.0f;
        int   bk = 0;
#pragma unroll
        for (int k = 0; k < PPT; ++k) {
            float dx = __fsub_rn(px[k], cx);
            float dy = __fsub_rn(py[k], cy);
            float dz = __fsub_rn(pz[k], cz);
            float d  = __builtin_fmaf(dz, dz,
                         __builtin_fmaf(dy, dy, __fmul_rn(dx, dx)));
            float nd = fminf(pd[k], d);
            pd[k] = nd;
            // strict >: earliest k wins (gi ascends with k) = first-occurrence
            if (nd > bd) { bd = nd; bk = k; }
        }
        u32 gi = (u32)(base + tid + TPB * bk);
        u64 key = ((u64)__float_as_uint(bd) << 32) | (u64)(~gi);

        // ---- wave max via DPP (VALU pipe) ----
        key = dpp_max64(key);              // valid in lane 63
        if (lane == 63) red[w] = key;      // plain store; barrier1 orders it
        __syncthreads();                   // barrier1

        if (w == 0) {
            // ---- combine 16 plain keys (real keys > 0; lanes 16+ feed 0) ----
            u64 k2 = (lane < NWAVE) ? red[lane] : 0ull;
            k2 = dpp_max16(k2);            // valid in lane 15
            // ---- ONE relaxed agent store publishes the block winner ----
            if (lane == 15) {
                u32 db  = (u32)(k2 >> 32);
                u32 idx = ~(u32)k2;        // = gi (fits 17 bits)
                __hip_atomic_store(&gsp[chunk],
                                   ((u64)db << 32) | ((u64)idx << 15) | (u64)it,
                                   __ATOMIC_RELAXED, __HIP_MEMORY_SCOPE_AGENT);
            }
            // ---- relaxed poll of the 16 slot words (ONE line; r8 protocol) --
            u64 v; bool ok;
            do {
                v  = (lane < NBLK)
                       ? __hip_atomic_load(&gsp[lane], __ATOMIC_RELAXED,
                                           __HIP_MEMORY_SCOPE_AGENT)
                       : 0ull;
                ok = (lane < NBLK) ? ((v & 0x7FFFull) == (u64)it) : true;
            } while (__ballot(ok) != ~0ull);
            u64 k3 = 0ull;
            if (lane < NBLK) {
                u32 db  = (u32)(v >> 32);
                u32 idx = (u32)((v >> 15) & 0x1FFFFu);
                k3 = ((u64)db << 32) | (u64)(~idx);
            }
            k3 = dpp_max16(k3);            // valid in lane 15
            if (lane == 15) {
                u32 widx = ~(u32)k3;
                if (chunk == 0) out[b * NSAMP + it] = (int)widx;
                bc = widx;                 // plain store; barrier2 orders it
            }
        }
        __syncthreads();                   // barrier2 (orders bc)

        u32 widx = bc;                     // barrier-ordered plain read
        cx = bxyz[3 * (size_t)widx + 0];   // same-address broadcast load
        cy = bxyz[3 * (size_t)widx + 1];
        cz = bxyz[3 * (size_t)widx + 2];
    }
}

extern "C" void kernel_launch(void* const* d_in, const int* in_sizes, int n_in,
                              void* d_out, int out_size, void* d_ws, size_t ws_size,
                              hipStream_t stream) {
    const float* xyz = (const float*)d_in[0];
    int* out = (int*)d_out;
    u64* gslot = (u64*)d_ws;   // [BATCH][2][NBLK] u64 = 4 KB

    hipLaunchKernelGGL(fps_init_kernel, dim3(1), dim3(512), 0, stream, gslot);
    hipLaunchKernelGGL(fps_kernel, dim3(BATCH * NBLK), dim3(TPB), 0, stream,
                       xyz, out, gslot);
}